// Round 1
// baseline (393.815 us; speedup 1.0000x reference)
//
#include <hip/hip_runtime.h>

static constexpr int   N_DIM        = 64;
static constexpr float HALF_LOG_2PI = 0.9189385332046727f;
static constexpr float CLIP_RATIO   = 0.2f;
static constexpr float DUAL_CLIP    = 5.0f;

__global__ void ppo_init(float* out) {
    if (threadIdx.x < 5) out[threadIdx.x] = 0.0f;
}

// One wave handles 4 rows/iteration via float4 loads (16B/lane).
// lanes [0..15] -> row 0 of chunk, [16..31] -> row 1, etc.
__global__ __launch_bounds__(256) void ppo_main(
    const float* __restrict__ mu_new,
    const float* __restrict__ sg_new,
    const float* __restrict__ mu_old,
    const float* __restrict__ sg_old,
    const float* __restrict__ act,
    const float* __restrict__ vnew,
    const float* __restrict__ vold,
    const float* __restrict__ adv,
    const float* __restrict__ ret,
    const float* __restrict__ wgt,
    float* __restrict__ out,
    int n_groups, int b_rows)
{
    const int t    = threadIdx.x;
    const int wave = t >> 6;        // 4 waves/block
    const int lane = t & 63;
    const int sub  = lane >> 4;     // which of the wave's 4 rows
    const int sl   = lane & 15;     // position within row (covers 4 elems)

    float accP = 0.f, accV = 0.f, accE = 0.f, accK = 0.f, accC = 0.f;

    for (int g = blockIdx.x; g < n_groups; g += gridDim.x) {
        const int base_row = g * 16 + wave * 4;      // this wave's 4 rows
        const int off      = base_row * N_DIM + lane * 4;

        const float4 mn = *(const float4*)(mu_new + off);
        const float4 sn = *(const float4*)(sg_new + off);
        const float4 mo = *(const float4*)(mu_old + off);
        const float4 so = *(const float4*)(sg_old + off);
        const float4 a  = *(const float4*)(act    + off);

        float qn = 0.f, qo = 0.f, en = 0.f, eo = 0.f;
#define PPO_COMP(c) {                                        \
        float rn = __builtin_amdgcn_rcpf(sn.c);              \
        float zn = (a.c - mn.c) * rn;  qn += zn * zn;        \
        float ro = __builtin_amdgcn_rcpf(so.c);              \
        float zo = (a.c - mo.c) * ro;  qo += zo * zo;        \
        en += __logf(sn.c);  eo += __logf(so.c); }
        PPO_COMP(x) PPO_COMP(y) PPO_COMP(z) PPO_COMP(w)
#undef PPO_COMP

        // per-lane partial log-probs (constants cancel, added analytically)
        float pn = -0.5f * qn - en;   // partial of logp_new + 64*HALF_LOG_2PI
        float po = -0.5f * qo - eo;   // partial of logp_old + 64*HALF_LOG_2PI

        // butterfly reduce within each 16-lane group -> full row sums
#pragma unroll
        for (int m = 1; m < 16; m <<= 1) {
            pn += __shfl_xor(pn, m, 16);
            po += __shfl_xor(po, m, 16);
            en += __shfl_xor(en, m, 16);
        }

        if (sl == 0) {
            const int r  = base_row + sub;
            const float w  = wgt[r];
            const float ad = adv[r];

            const float ratio = __expf(pn - po);
            const float s1 = ratio * ad;
            const float rc = fminf(fmaxf(ratio, 1.0f - CLIP_RATIO), 1.0f + CLIP_RATIO);
            const float s2 = rc * ad;
            float cl = fminf(s1, s2);
            cl = fmaxf(cl, DUAL_CLIP * ad);
            accP += cl * w;

            const float entropy = (float)N_DIM * (0.5f + HALF_LOG_2PI) + en;
            accE += entropy * w;

            const float vn = vnew[r], vo = vold[r], rt = ret[r];
            const float vc = vo + fminf(fmaxf(vn - vo, -CLIP_RATIO), CLIP_RATIO);
            const float d1 = rt - vn, d2 = rt - vc;
            accV += fmaxf(d1 * d1, d2 * d2) * w;

            accK += (po - pn);
            accC += (fabsf(ratio - 1.0f) > CLIP_RATIO) ? 1.0f : 0.0f;
        }
    }

    // writer lanes are 0,16,32,48 -> xor 16, 32 combines them onto lane 0
#pragma unroll
    for (int m = 16; m < 64; m <<= 1) {
        accP += __shfl_xor(accP, m, 64);
        accV += __shfl_xor(accV, m, 64);
        accE += __shfl_xor(accE, m, 64);
        accK += __shfl_xor(accK, m, 64);
        accC += __shfl_xor(accC, m, 64);
    }

    __shared__ float red[4][5];
    if (lane == 0) {
        red[wave][0] = accP; red[wave][1] = accV; red[wave][2] = accE;
        red[wave][3] = accK; red[wave][4] = accC;
    }
    __syncthreads();

    if (t == 0) {
        float P = 0.f, V = 0.f, E = 0.f, K = 0.f, C = 0.f;
#pragma unroll
        for (int wv = 0; wv < 4; ++wv) {
            P += red[wv][0]; V += red[wv][1]; E += red[wv][2];
            K += red[wv][3]; C += red[wv][4];
        }
        const float invB = 1.0f / (float)b_rows;
        atomicAdd(&out[0], -P * invB);          // policy_loss
        atomicAdd(&out[1], 0.5f * V * invB);    // value_loss
        atomicAdd(&out[2], E * invB);           // entropy_loss
        atomicAdd(&out[3], K * invB);           // approx_kl
        atomicAdd(&out[4], C * invB);           // clipfrac
    }
}

extern "C" void kernel_launch(void* const* d_in, const int* in_sizes, int n_in,
                              void* d_out, int out_size, void* d_ws, size_t ws_size,
                              hipStream_t stream) {
    const float* mu_new = (const float*)d_in[0];
    const float* sg_new = (const float*)d_in[1];
    const float* mu_old = (const float*)d_in[2];
    const float* sg_old = (const float*)d_in[3];
    const float* act    = (const float*)d_in[4];
    const float* vnew   = (const float*)d_in[5];
    const float* vold   = (const float*)d_in[6];
    const float* adv    = (const float*)d_in[7];
    const float* ret    = (const float*)d_in[8];
    const float* wgt    = (const float*)d_in[9];
    float* out = (float*)d_out;

    const int b_rows   = in_sizes[5];       // B from value_new
    const int n_groups = b_rows / 16;       // 16 rows per block-iteration

    ppo_init<<<1, 64, 0, stream>>>(out);

    const int grid = 2048;                  // grid-stride: 8 iters/block at B=262144
    ppo_main<<<grid, 256, 0, stream>>>(mu_new, sg_new, mu_old, sg_old, act,
                                       vnew, vold, adv, ret, wgt,
                                       out, n_groups, b_rows);
}

// Round 2
// 322.879 us; speedup vs baseline: 1.2197x; 1.2197x over previous
//
#include <hip/hip_runtime.h>

static constexpr int   N_DIM        = 64;
static constexpr float HALF_LOG_2PI = 0.9189385332046727f;
static constexpr float CLIP_RATIO   = 0.2f;
static constexpr float DUAL_CLIP    = 5.0f;
static constexpr int   GRID         = 2048;   // main-kernel blocks

// ---------------------------------------------------------------------------
// Main kernel: one wave handles 4 rows/iteration via float4 loads (16B/lane).
// lanes [0..15] -> row 0 of chunk, [16..31] -> row 1, etc.
// Per-block partials go to ws (column-major: ws[k*GRID + blockIdx]) — NO
// global atomics (10240 same-line atomics were serializing ~200 us in R1).
// ---------------------------------------------------------------------------
__global__ __launch_bounds__(256) void ppo_main(
    const float* __restrict__ mu_new,
    const float* __restrict__ sg_new,
    const float* __restrict__ mu_old,
    const float* __restrict__ sg_old,
    const float* __restrict__ act,
    const float* __restrict__ vnew,
    const float* __restrict__ vold,
    const float* __restrict__ adv,
    const float* __restrict__ ret,
    const float* __restrict__ wgt,
    float* __restrict__ ws,
    int n_groups, int b_rows)
{
    const int t    = threadIdx.x;
    const int wave = t >> 6;        // 4 waves/block
    const int lane = t & 63;
    const int sub  = lane >> 4;     // which of the wave's 4 rows
    const int sl   = lane & 15;     // position within row (covers 4 elems)

    float accP = 0.f, accV = 0.f, accE = 0.f, accK = 0.f, accC = 0.f;

    // ---- value-loss pass: fully vectorized over rows, coalesced, no
    // divergence (removes vnew/vold/ret from the divergent per-row tail) ----
    {
        const int gtid = blockIdx.x * 256 + t;
        const int tot  = gridDim.x * 256;
        for (int r = gtid; r < b_rows; r += tot) {
            const float vn = vnew[r], vo = vold[r], rt = ret[r], w = wgt[r];
            const float vc = vo + fminf(fmaxf(vn - vo, -CLIP_RATIO), CLIP_RATIO);
            const float d1 = rt - vn, d2 = rt - vc;
            accV += fmaxf(d1 * d1, d2 * d2) * w;
        }
    }

    // ---- policy / entropy / kl / clipfrac pass ----
    for (int g = blockIdx.x; g < n_groups; g += gridDim.x) {
        const int base_row = g * 16 + wave * 4;      // this wave's 4 rows
        const int off      = base_row * N_DIM + lane * 4;

        const float4 mn = *(const float4*)(mu_new + off);
        const float4 sn = *(const float4*)(sg_new + off);
        const float4 mo = *(const float4*)(mu_old + off);
        const float4 so = *(const float4*)(sg_old + off);
        const float4 a  = *(const float4*)(act    + off);

        // prefetch per-row scalars early so their latency overlaps the
        // compute + swizzle chain below
        float w = 0.f, ad = 0.f;
        if (sl == 0) {
            const int r = base_row + sub;
            w  = wgt[r];
            ad = adv[r];
        }

        float qn = 0.f, qo = 0.f, en = 0.f, eo = 0.f;
#define PPO_COMP(c) {                                        \
        float rn = __builtin_amdgcn_rcpf(sn.c);              \
        float zn = (a.c - mn.c) * rn;  qn += zn * zn;        \
        float ro = __builtin_amdgcn_rcpf(so.c);              \
        float zo = (a.c - mo.c) * ro;  qo += zo * zo;        \
        en += __logf(sn.c);  eo += __logf(so.c); }
        PPO_COMP(x) PPO_COMP(y) PPO_COMP(z) PPO_COMP(w)
#undef PPO_COMP

        // per-lane partial log-probs (HALF_LOG_2PI constants cancel)
        float pn = -0.5f * qn - en;
        float po = -0.5f * qo - eo;

        // butterfly reduce within each 16-lane group -> full row sums
#pragma unroll
        for (int m = 1; m < 16; m <<= 1) {
            pn += __shfl_xor(pn, m, 16);
            po += __shfl_xor(po, m, 16);
            en += __shfl_xor(en, m, 16);
        }

        if (sl == 0) {
            const float ratio = __expf(pn - po);
            const float s1 = ratio * ad;
            const float rc = fminf(fmaxf(ratio, 1.0f - CLIP_RATIO), 1.0f + CLIP_RATIO);
            const float s2 = rc * ad;
            float cl = fminf(s1, s2);
            cl = fmaxf(cl, DUAL_CLIP * ad);
            accP += cl * w;

            accE += ((float)N_DIM * (0.5f + HALF_LOG_2PI) + en) * w;
            accK += (po - pn);
            accC += (fabsf(ratio - 1.0f) > CLIP_RATIO) ? 1.0f : 0.0f;
        }
    }

    // wave-level reduce (all lanes hold accV; P/E/K/C live on lanes 0,16,32,48)
#pragma unroll
    for (int m = 1; m < 64; m <<= 1) accV += __shfl_xor(accV, m, 64);
#pragma unroll
    for (int m = 16; m < 64; m <<= 1) {
        accP += __shfl_xor(accP, m, 64);
        accE += __shfl_xor(accE, m, 64);
        accK += __shfl_xor(accK, m, 64);
        accC += __shfl_xor(accC, m, 64);
    }

    __shared__ float red[4][5];
    if (lane == 0) {
        red[wave][0] = accP; red[wave][1] = accV; red[wave][2] = accE;
        red[wave][3] = accK; red[wave][4] = accC;
    }
    __syncthreads();

    if (t == 0) {
        float s[5] = {0.f, 0.f, 0.f, 0.f, 0.f};
#pragma unroll
        for (int wv = 0; wv < 4; ++wv)
#pragma unroll
            for (int k = 0; k < 5; ++k) s[k] += red[wv][k];
        // column-major so the reduce kernel reads coalesced
#pragma unroll
        for (int k = 0; k < 5; ++k) ws[k * GRID + blockIdx.x] = s[k];
    }
}

// ---------------------------------------------------------------------------
// Final reduce: one block sums GRID partials per output and writes d_out.
// ---------------------------------------------------------------------------
__global__ __launch_bounds__(256) void ppo_reduce(
    const float* __restrict__ ws, float* __restrict__ out, int b_rows)
{
    const int t    = threadIdx.x;
    const int wave = t >> 6;
    const int lane = t & 63;
    __shared__ float red[4];

    const float invB = 1.0f / (float)b_rows;

    for (int k = 0; k < 5; ++k) {
        float v = 0.f;
        for (int i = t; i < GRID; i += 256) v += ws[k * GRID + i];
#pragma unroll
        for (int m = 1; m < 64; m <<= 1) v += __shfl_xor(v, m, 64);
        if (lane == 0) red[wave] = v;
        __syncthreads();
        if (t == 0) {
            float s = red[0] + red[1] + red[2] + red[3];
            float o;
            if      (k == 0) o = -s * invB;          // policy_loss
            else if (k == 1) o = 0.5f * s * invB;    // value_loss
            else             o = s * invB;           // entropy / kl / clipfrac
            out[k] = o;
        }
        __syncthreads();
    }
}

extern "C" void kernel_launch(void* const* d_in, const int* in_sizes, int n_in,
                              void* d_out, int out_size, void* d_ws, size_t ws_size,
                              hipStream_t stream) {
    const float* mu_new = (const float*)d_in[0];
    const float* sg_new = (const float*)d_in[1];
    const float* mu_old = (const float*)d_in[2];
    const float* sg_old = (const float*)d_in[3];
    const float* act    = (const float*)d_in[4];
    const float* vnew   = (const float*)d_in[5];
    const float* vold   = (const float*)d_in[6];
    const float* adv    = (const float*)d_in[7];
    const float* ret    = (const float*)d_in[8];
    const float* wgt    = (const float*)d_in[9];
    float* out = (float*)d_out;
    float* ws  = (float*)d_ws;

    const int b_rows   = in_sizes[5];       // B from value_new
    const int n_groups = b_rows / 16;       // 16 rows per block-iteration

    ppo_main<<<GRID, 256, 0, stream>>>(mu_new, sg_new, mu_old, sg_old, act,
                                       vnew, vold, adv, ret, wgt,
                                       ws, n_groups, b_rows);
    ppo_reduce<<<1, 256, 0, stream>>>(ws, out, b_rows);
}

// Round 3
// 315.526 us; speedup vs baseline: 1.2481x; 1.0233x over previous
//
#include <hip/hip_runtime.h>

static constexpr int   N_DIM        = 64;
static constexpr float HALF_LOG_2PI = 0.9189385332046727f;
static constexpr float CLIP_RATIO   = 0.2f;
static constexpr float DUAL_CLIP    = 5.0f;
static constexpr int   GRID         = 2048;   // main-kernel blocks
static constexpr float ENT_CONST    = (float)N_DIM * (0.5f + HALF_LOG_2PI); // per-row entropy const
static constexpr float ENT_C16      = ENT_CONST / 16.0f;  // spread over 16 lanes

// per-lane partials for one 4-row set: en = sum log(sigma_new) over this
// lane's 4 elems; d = partial of (logp_new - logp_old) (HALF_LOG_2PI cancels)
__device__ __forceinline__ void ppo_set(const float4& mn, const float4& sn,
                                        const float4& mo, const float4& so,
                                        const float4& a,
                                        float& en_out, float& d_out)
{
    float qn = 0.f, qo = 0.f, en = 0.f, eo = 0.f;
#define PPO_COMP(c) {                                        \
        float rn = __builtin_amdgcn_rcpf(sn.c);              \
        float zn = (a.c - mn.c) * rn;  qn += zn * zn;        \
        float ro = __builtin_amdgcn_rcpf(so.c);              \
        float zo = (a.c - mo.c) * ro;  qo += zo * zo;        \
        en += __logf(sn.c);  eo += __logf(so.c); }
    PPO_COMP(x) PPO_COMP(y) PPO_COMP(z) PPO_COMP(w)
#undef PPO_COMP
    en_out = en;
    d_out  = 0.5f * (qo - qn) + (eo - en);   // pn - po, per-lane partial
}

// ---------------------------------------------------------------------------
// Main kernel. One wave handles 8 rows/iteration (two 4-row sets) via 10
// float4 loads issued up front (MLP). lanes [0..15] -> row 0 of a set, etc.
// Only `d` goes through the 16-lane butterfly (exp is the only per-row
// nonlinearity); kl/entropy accumulate per-lane; the scalar tail runs
// redundantly on all 16 lanes (exact 16x, scaled by 1/16 at the end) to
// avoid divergence. Per-block partials go to ws — no global atomics.
// ---------------------------------------------------------------------------
__global__ __launch_bounds__(256) void ppo_main(
    const float* __restrict__ mu_new,
    const float* __restrict__ sg_new,
    const float* __restrict__ mu_old,
    const float* __restrict__ sg_old,
    const float* __restrict__ act,
    const float* __restrict__ vnew,
    const float* __restrict__ vold,
    const float* __restrict__ adv,
    const float* __restrict__ ret,
    const float* __restrict__ wgt,
    float* __restrict__ ws,
    int b_rows)
{
    const int t    = threadIdx.x;
    const int wave = t >> 6;        // 4 waves/block
    const int lane = t & 63;
    const int sub  = lane >> 4;     // row within a 4-row set

    float accP = 0.f, accV = 0.f, accE = 0.f, accK = 0.f, accC = 0.f;

    // ---- value-loss pass: one row per thread, coalesced, no divergence ----
    {
        const int r = blockIdx.x * 256 + t;
        if (r < b_rows) {
            const float vn = vnew[r], vo = vold[r], rt = ret[r], w = wgt[r];
            const float vc = vo + fminf(fmaxf(vn - vo, -CLIP_RATIO), CLIP_RATIO);
            const float d1 = rt - vn, d2 = rt - vc;
            accV += fmaxf(d1 * d1, d2 * d2) * w;
        }
    }

    // ---- policy / entropy / kl / clipfrac: 32 rows per block-step ----
    const int n_g = b_rows >> 5;
    for (int g = blockIdx.x; g < n_g; g += gridDim.x) {
        const int row0 = g * 32 + wave * 8;          // first of this wave's 8 rows
        const int r0   = row0 + sub;                 // set-0 row for this lane
        const int r1   = r0 + 4;                     // set-1 row
        const int off0 = row0 * N_DIM + lane * 4;
        const int off1 = off0 + 4 * N_DIM;

        // issue all 10 vector loads + 4 broadcast scalars before any use
        const float4 mn0 = *(const float4*)(mu_new + off0);
        const float4 sn0 = *(const float4*)(sg_new + off0);
        const float4 mo0 = *(const float4*)(mu_old + off0);
        const float4 so0 = *(const float4*)(sg_old + off0);
        const float4 a0  = *(const float4*)(act    + off0);
        const float4 mn1 = *(const float4*)(mu_new + off1);
        const float4 sn1 = *(const float4*)(sg_new + off1);
        const float4 mo1 = *(const float4*)(mu_old + off1);
        const float4 so1 = *(const float4*)(sg_old + off1);
        const float4 a1  = *(const float4*)(act    + off1);
        const float w0 = wgt[r0], ad0 = adv[r0];
        const float w1 = wgt[r1], ad1 = adv[r1];

        float en0, d0, en1, d1;
        ppo_set(mn0, sn0, mo0, so0, a0, en0, d0);
        ppo_set(mn1, sn1, mo1, so1, a1, en1, d1);

        // approx_kl = mean(po - pn): linear -> per-lane, pre-reduction
        accK -= (d0 + d1);
        // entropy: w broadcast within the 16-lane group -> per-lane
        accE += w0 * (en0 + ENT_C16) + w1 * (en1 + ENT_C16);

        // only d needs the row reduction (feeds exp)
#pragma unroll
        for (int m = 1; m < 16; m <<= 1) {
            d0 += __shfl_xor(d0, m, 16);
            d1 += __shfl_xor(d1, m, 16);
        }

        // scalar tail on ALL lanes (identical within group; 16x accounted later)
        {
            const float ratio = __expf(d0);
            const float rc = fminf(fmaxf(ratio, 1.f - CLIP_RATIO), 1.f + CLIP_RATIO);
            float cl = fminf(ratio * ad0, rc * ad0);
            cl = fmaxf(cl, DUAL_CLIP * ad0);
            accP += cl * w0;
            accC += (fabsf(ratio - 1.f) > CLIP_RATIO) ? 1.f : 0.f;
        }
        {
            const float ratio = __expf(d1);
            const float rc = fminf(fmaxf(ratio, 1.f - CLIP_RATIO), 1.f + CLIP_RATIO);
            float cl = fminf(ratio * ad1, rc * ad1);
            cl = fmaxf(cl, DUAL_CLIP * ad1);
            accP += cl * w1;
            accC += (fabsf(ratio - 1.f) > CLIP_RATIO) ? 1.f : 0.f;
        }
    }

    accP *= 0.0625f;   // undo 16x redundancy (exact: power of 2)
    accC *= 0.0625f;

    // full-wave butterfly for all 5 accumulators
#pragma unroll
    for (int m = 1; m < 64; m <<= 1) {
        accP += __shfl_xor(accP, m, 64);
        accV += __shfl_xor(accV, m, 64);
        accE += __shfl_xor(accE, m, 64);
        accK += __shfl_xor(accK, m, 64);
        accC += __shfl_xor(accC, m, 64);
    }

    __shared__ float red[4][5];
    if (lane == 0) {
        red[wave][0] = accP; red[wave][1] = accV; red[wave][2] = accE;
        red[wave][3] = accK; red[wave][4] = accC;
    }
    __syncthreads();

    if (t == 0) {
        float s[5] = {0.f, 0.f, 0.f, 0.f, 0.f};
#pragma unroll
        for (int wv = 0; wv < 4; ++wv)
#pragma unroll
            for (int k = 0; k < 5; ++k) s[k] += red[wv][k];
        // column-major so the reduce kernel reads coalesced
#pragma unroll
        for (int k = 0; k < 5; ++k) ws[k * GRID + blockIdx.x] = s[k];
    }
}

// ---------------------------------------------------------------------------
// Final reduce: 5 waves, one output each — no syncthreads, no atomics.
// ---------------------------------------------------------------------------
__global__ __launch_bounds__(320) void ppo_reduce(
    const float* __restrict__ ws, float* __restrict__ out, int b_rows)
{
    const int wave = threadIdx.x >> 6;   // 0..4 -> output index
    const int lane = threadIdx.x & 63;

    float v = 0.f;
    for (int i = lane; i < GRID; i += 64) v += ws[wave * GRID + i];
#pragma unroll
    for (int m = 1; m < 64; m <<= 1) v += __shfl_xor(v, m, 64);

    if (lane == 0) {
        const float invB = 1.0f / (float)b_rows;
        float o;
        if      (wave == 0) o = -v * invB;        // policy_loss
        else if (wave == 1) o = 0.5f * v * invB;  // value_loss
        else                o = v * invB;         // entropy / kl / clipfrac
        out[wave] = o;
    }
}

extern "C" void kernel_launch(void* const* d_in, const int* in_sizes, int n_in,
                              void* d_out, int out_size, void* d_ws, size_t ws_size,
                              hipStream_t stream) {
    const float* mu_new = (const float*)d_in[0];
    const float* sg_new = (const float*)d_in[1];
    const float* mu_old = (const float*)d_in[2];
    const float* sg_old = (const float*)d_in[3];
    const float* act    = (const float*)d_in[4];
    const float* vnew   = (const float*)d_in[5];
    const float* vold   = (const float*)d_in[6];
    const float* adv    = (const float*)d_in[7];
    const float* ret    = (const float*)d_in[8];
    const float* wgt    = (const float*)d_in[9];
    float* out = (float*)d_out;
    float* ws  = (float*)d_ws;

    const int b_rows = in_sizes[5];     // B from value_new

    ppo_main<<<GRID, 256, 0, stream>>>(mu_new, sg_new, mu_old, sg_old, act,
                                       vnew, vold, adv, ret, wgt,
                                       ws, b_rows);
    ppo_reduce<<<1, 320, 0, stream>>>(ws, out, b_rows);
}